// Round 1
// 26.982 us; speedup vs baseline: 1.0230x; 1.0230x over previous
//
#include <hip/hip_runtime.h>

// VQ-VAE quantizer forward — R12: 2 blocks/CU for phase overlap.
//   inputs  [B=8, C=64, T=16, H=32, W=32] fp32   (layout: b*C*THW + c*THW + r)
//   codebook[K=512, C=64] fp32
// outputs: q_z [B,C,T,H,W] fp32, vq_loss, commitment_loss (concat flat)
//
// dist(p,k) = ||e_k||^2 - 2*x_p.e_k. Block builds the whole codebook (bf16,
// pre-scaled by -2, XOR-swizzled) + fp32 norms in LDS. MFMA C-init = ||e||^2
// => acc IS the distance. 9-bit code packed into mantissa LSBs => argmin is
// pure f32 min. Loss via ||e-x||^2 = ||x||^2 + d_best.
//
// R11: x loaded as float4 (16 lanes x 16B = 256B full-line segments); float4's
// 4 positions map to the 4 MFMA tiles (pos rw + 4*m + tt). q stores NT (exact
// bytes, keeps L2/L3 clean).
// R12: grid 256x512 -> 512x256. LDS footprint is 68.6 KB, so TWO blocks fit
// per CU (137 KB <= 160 KB), but the old grid (1 block/CU) never used that.
// Two co-resident blocks have independent barrier domains: one block's
// x-load/barrier-drain overlaps the other's MFMA scan / store epilogue.
// Wave geometry (64 pos/wave, 4-wave block, 256 pos/block) is unchanged, so
// all R10/R11 coalescing/exact-bytes properties carry over. Codebook build
// runs 2x per CU (L2-hot, hidden under overlap).

#define K_CODES 512
#define NCH     64
#define THW     16384
#define NPOS    131072
#define NELEM   8388608
#define NBLK    512

typedef __attribute__((ext_vector_type(8))) short bf16x8;
typedef __attribute__((ext_vector_type(4))) float f32x4;

__device__ __forceinline__ unsigned short f32_bf16(float f) {
    unsigned u = __float_as_uint(f);
    u += 0x7FFFu + ((u >> 16) & 1u);          // round-to-nearest-even
    return (unsigned short)(u >> 16);
}

__global__ __launch_bounds__(256, 2) void vq_main(
        const float* __restrict__ x,
        const float* __restrict__ cb,
        float* __restrict__ out,
        float* __restrict__ partials) {
    __shared__ __align__(16) unsigned char lds_cb[65536];   // bf16(-2e), swizzled
    __shared__ __align__(16) float lds_norm[K_CODES];
    __shared__ int lds_idx[256];

    const int tid  = threadIdx.x;
    const int lane = tid & 63;
    const int w    = tid >> 6;       // wave 0..3
    const int g    = lane >> 4;      // 16-lane group 0..3
    const int r15  = lane & 15;

    const int blk  = blockIdx.x;
    const int b    = blk >> 6;                 // batch (64 blocks per batch)
    const int rblk = (blk & 63) << 8;          // 256 positions per block
    const int rw   = rblk + w * 64;            // wave's first position
    const float* xb = x + (size_t)b * (NCH * THW);

    // ---- x loads: float4 per (kf,j); 16 lanes x 16B = 256B contiguous ----
    // lane(g,r15) gets positions {rw+4*r15+tt, tt=0..3} of channel kf*32+g*8+j
    float4 xv[2][8];
    #pragma unroll
    for (int kf = 0; kf < 2; ++kf)
        #pragma unroll
        for (int j = 0; j < 8; ++j)
            xv[kf][j] = *(const float4*)(xb + (size_t)(kf * 32 + g * 8 + j) * THW
                                            + rw + 4 * r15);

    // ---- build FULL codebook in LDS (16 rounds; overlaps x latency):
    // thread t owns logical 16B chunk j8=t&7 of code row r=(t>>3)+32*rr,
    // stored at physical chunk j8^(r&7) => swizzled, matches scan map. ----
    #pragma unroll
    for (int rr = 0; rr < 16; ++rr) {
        const int r  = (tid >> 3) + (rr << 5);
        const int j8 = tid & 7;
        const float4* cr = (const float4*)(cb + r * NCH + j8 * 8);
        const float4 e0 = cr[0];
        const float4 e1 = cr[1];
        float s = e0.x * e0.x;
        s = fmaf(e0.y, e0.y, s); s = fmaf(e0.z, e0.z, s); s = fmaf(e0.w, e0.w, s);
        s = fmaf(e1.x, e1.x, s); s = fmaf(e1.y, e1.y, s); s = fmaf(e1.z, e1.z, s);
        s = fmaf(e1.w, e1.w, s);
        s += __shfl_xor(s, 1); s += __shfl_xor(s, 2); s += __shfl_xor(s, 4);
        if (j8 == 0) lds_norm[r] = s;          // ||e_r||^2 (unscaled)
        bf16x8 pk;
        pk[0] = (short)f32_bf16(-2.f * e0.x);
        pk[1] = (short)f32_bf16(-2.f * e0.y);
        pk[2] = (short)f32_bf16(-2.f * e0.z);
        pk[3] = (short)f32_bf16(-2.f * e0.w);
        pk[4] = (short)f32_bf16(-2.f * e1.x);
        pk[5] = (short)f32_bf16(-2.f * e1.y);
        pk[6] = (short)f32_bf16(-2.f * e1.z);
        pk[7] = (short)f32_bf16(-2.f * e1.w);
        *(bf16x8*)(lds_cb + r * 128 + ((j8 ^ (r & 7)) * 16)) = pk;
    }

    // ---- convert x to bf16 A-frags + fp32 ||x||^2 partial ----
    // af[tt][kf][j] = bf16(x[pos rw+4*r15+tt][ch kf*32+g*8+j])
    bf16x8 af[4][2];
    float  xn = 0.f;
    #pragma unroll
    for (int kf = 0; kf < 2; ++kf)
        #pragma unroll
        for (int j = 0; j < 8; ++j) {
            const float4 v = xv[kf][j];
            xn = fmaf(v.x, v.x, xn);
            xn = fmaf(v.y, v.y, xn);
            xn = fmaf(v.z, v.z, xn);
            xn = fmaf(v.w, v.w, xn);
            af[0][kf][j] = (short)f32_bf16(v.x);
            af[1][kf][j] = (short)f32_bf16(v.y);
            af[2][kf][j] = (short)f32_bf16(v.z);
            af[3][kf][j] = (short)f32_bf16(v.w);
        }

    __syncthreads();   // codebook + norms resident

    // ---- scan all 512 codes ----
    float best[4][4];
    #pragma unroll
    for (int tt = 0; tt < 4; ++tt)
        #pragma unroll
        for (int i = 0; i < 4; ++i) best[tt][i] = 3.4e38f;

    const int swz = (r15 & 7) << 4;
    const unsigned char* pb0 = lds_cb + r15 * 128 + ((g * 16) ^ swz);
    const unsigned char* pb1 = lds_cb + r15 * 128 + ((64 + g * 16) ^ swz);
    #pragma unroll
    for (int f = 0; f < 32; ++f) {
        const bf16x8 b0 = *(const bf16x8*)(pb0 + f * 2048);
        const bf16x8 b1 = *(const bf16x8*)(pb1 + f * 2048);
        const float nrm = lds_norm[f * 16 + r15];
        const unsigned code = (unsigned)(f * 16 + r15);   // lane's B-column
        #pragma unroll
        for (int tt = 0; tt < 4; ++tt) {
            f32x4 acc = {nrm, nrm, nrm, nrm};
            acc = __builtin_amdgcn_mfma_f32_16x16x32_bf16(af[tt][0], b0, acc, 0, 0, 0);
            acc = __builtin_amdgcn_mfma_f32_16x16x32_bf16(af[tt][1], b1, acc, 0, 0, 0);
            #pragma unroll
            for (int i = 0; i < 4; ++i) {   // acc[i]: pos rw+4*(4g+i)+tt
                const float pkv = __uint_as_float(
                    (__float_as_uint(acc[i]) & ~511u) | code);
                best[tt][i] = fminf(best[tt][i], pkv);
            }
        }
    }

    // ---- wave-local argmin (reduce over r15 = code axis) ----
    float sd = 0.f;
    int   idxs[4][4];
    #pragma unroll
    for (int tt = 0; tt < 4; ++tt) {
        #pragma unroll
        for (int i = 0; i < 4; ++i) {
            float v = best[tt][i];
            #pragma unroll
            for (int off = 8; off; off >>= 1) v = fminf(v, __shfl_xor(v, off));
            sd += v;                                // replicated x16 per group
            idxs[tt][i] = (int)(__float_as_uint(v) & 511u);
        }
    }
    if (r15 == 0) {                   // same-wave RAW only (no barrier needed)
        #pragma unroll
        for (int tt = 0; tt < 4; ++tt)
            #pragma unroll
            for (int i = 0; i < 4; ++i)
                lds_idx[w * 64 + 16 * g + 4 * i + tt] = idxs[tt][i];
    }
    // per-wave loss partial: sum(||x||^2) + sum(d_best)/16
    float part = fmaf(sd, 0.0625f, xn);
    #pragma unroll
    for (int off = 32; off; off >>= 1) part += __shfl_down(part, off);
    if (lane == 0) partials[blk * 4 + w] = part;

    // ---- wave-local epilogue: lane = one position; q from fp32 cb (L2-hot);
    // nontemporal stores (exact bytes, keeps L3 clean for x) ----
    const int bc = lds_idx[tid];                       // tid == w*64 + lane
    float* oq = out + (size_t)b * (NCH * THW) + (rblk + tid);
    const float4* crow = (const float4*)(cb + (size_t)bc * NCH);
    #pragma unroll
    for (int jj = 0; jj < 16; ++jj) {
        const float4 e = crow[jj];
        const size_t c0 = (size_t)(jj * 4) * THW;
        __builtin_nontemporal_store(e.x, oq + c0);
        __builtin_nontemporal_store(e.y, oq + c0 + THW);
        __builtin_nontemporal_store(e.z, oq + c0 + 2 * THW);
        __builtin_nontemporal_store(e.w, oq + c0 + 3 * THW);
    }
}

__global__ void vq_finalize(const float* __restrict__ partials,
                            float* __restrict__ out) {
    const int tid = threadIdx.x;   // 256 threads, 2048 partials, fixed order
    float v = 0.f;
    #pragma unroll
    for (int k = 0; k < 8; ++k) v += partials[tid + 256 * k];
    #pragma unroll
    for (int off = 32; off; off >>= 1) v += __shfl_down(v, off);
    __shared__ float ws[4];
    if ((tid & 63) == 0) ws[tid >> 6] = v;
    __syncthreads();
    if (tid == 0) {
        const float total  = (ws[0] + ws[1]) + (ws[2] + ws[3]);
        const float commit = total * (1.0f / (float)NELEM);
        out[NELEM]     = 0.25f * commit;   // vq_loss
        out[NELEM + 1] = commit;           // commitment_loss
    }
}

extern "C" void kernel_launch(void* const* d_in, const int* in_sizes, int n_in,
                              void* d_out, int out_size, void* d_ws, size_t ws_size,
                              hipStream_t stream) {
    const float* x  = (const float*)d_in[0];
    const float* cb = (const float*)d_in[1];
    float* out      = (float*)d_out;
    float* partials = (float*)d_ws;        // 2048 floats

    vq_main<<<NBLK, 256, 0, stream>>>(x, cb, out, partials);
    vq_finalize<<<1, 256, 0, stream>>>(partials, out);
}